// Round 13
// baseline (1539.302 us; speedup 1.0000x reference)
//
#include <hip/hip_runtime.h>
#include <hip/hip_cooperative_groups.h>
#include <math.h>

namespace cg = cooperative_groups;

#define N_NODES 50000
#define N_EDGES 800000
#define IN_DIM 128
#define ED_DIM 32
#define HC 64
#define NG 64
#define NCL 2
#define NEG_SLOPE 0.2f
#define LN_EPS 1e-5f
#define NBLK1 196     // ceil(50000/256)
#define NB_TILE 3125  // 50000/16 xw tiles == 800000/256 chunks
#define NVB_B 12500   // phase B virtual blocks: {xw,edge,hist,edge} x 3125
#define NVB_D 3321    // 196 row_start finalize + 3125 perm
#define NVB_AGG 12500 // 4 nodes per vblock
#define NVB_POOL 391
#define NVB_HEAD 16

struct MParams {
    const float *x, *ea, *W1, *as1, *ad1, *We1, *ae1, *b1;
    const float *W2, *as2, *ad2, *We2, *ae2, *b2, *g1, *be1;
    const float *fw1, *fb1, *g2, *be2, *fw2, *fb2;
    const int *srcI, *dstI, *batch;
    int *cnt, *row_start, *rank_e, *tmp_ex, *bsum;
    int2 *perm_src;
    float4 *ale8;
    float *xw1, *als1, *ald1, *xw2, *als2, *ald2, *h2, *pooled, *out;
};

// ================= MEGA: whole pipeline, one cooperative dispatch =================
// 18KB LDS -> 8 blocks/CU (32 waves) for all phases. 7 grid.sync()s replace ~9
// launch gaps (~130us measured). Every phase is a bit-exact port of a
// harness-verified kernel (R7 chunked-xw, R10 staged-edge math, R11 agg1x, R3 agg2).
__global__ __launch_bounds__(256, 8) void mega(MParams p) {
    cg::grid_group grid = cg::this_grid();
    __shared__ float smem[4608];   // 18KB union
    int t = threadIdx.x;
    int nb = gridDim.x;

    // ---- Phase A: zero cnt + pooled (replaces host memsets) ----
    for (int i = blockIdx.x * 256 + t; i < N_NODES; i += nb * 256) p.cnt[i] = 0;
    for (int i = blockIdx.x * 256 + t; i < NG * HC; i += nb * 256) p.pooled[i] = 0.f;
    grid.sync();

    // ---- Phase B: {xw1-chunked | edge-proj (128/vb, split-k) | hist} ----
    for (int vb = blockIdx.x; vb < NVB_B; vb += nb) {
        int job = vb & 3;
        int bid = vb >> 2;
        if (job == 0) {
            // xw1, W1 in 4 chunks of k=32 (R7-verified, k ascending = bit-exact)
            float* sX = smem;            // 16 x 128
            float* sW = smem + 2048;     // 32 x 64
            int nbase = bid * 16;
            for (int i = t; i < 16 * IN_DIM; i += 256)
                sX[i] = p.x[(long long)nbase * IN_DIM + i];
            int sub = t >> 6, j = t & 63;
            float acc[4] = {0.f, 0.f, 0.f, 0.f};
            for (int c = 0; c < IN_DIM; c += 32) {
                if (c) __syncthreads();
                for (int i = t; i < 32 * HC; i += 256) sW[i] = p.W1[c * HC + i];
                __syncthreads();
                #pragma unroll 8
                for (int kk = 0; kk < 32; ++kk) {
                    float wv = sW[kk * HC + j];
                    #pragma unroll
                    for (int q = 0; q < 4; ++q)
                        acc[q] += sX[(sub + 4 * q) * IN_DIM + c + kk] * wv;
                }
            }
            float as_ = p.as1[j], ad_ = p.ad1[j];
            #pragma unroll
            for (int q = 0; q < 4; ++q) {
                int n = nbase + sub + 4 * q;
                p.xw1[(long long)n * HC + j] = acc[q];
                float vs = acc[q] * as_, vd = acc[q] * ad_;
                #pragma unroll
                for (int m = 1; m < 16; m <<= 1) { vs += __shfl_xor(vs, m); vd += __shfl_xor(vd, m); }
                if ((j & 15) == 0) {
                    int h = j >> 4;
                    p.als1[n * 4 + h] = vs; p.ald1[n * 4 + h] = vd;
                }
            }
        } else if (job == 2) {
            // degree histogram
            int e = bid * 256 + t;
            p.rank_e[e] = atomicAdd(&p.cnt[p.dstI[e]], 1);
        } else {
            // edge projection: 128 edges/vblock, coalesced-staged (R10 mechanism),
            // split-k: t<128 -> layer1 (k0..3), t>=128 -> layer2 (k4..7). Per-output
            // accumulation order over c=0..31 identical to verified form.
            int ebid = (bid << 1) | (job >> 1);   // job==1 -> even, job==3 -> odd
            float* sVe = smem;            // 256
            float* sE  = smem + 256;      // 128 x 33 (padded, bank-conflict-free)
            {
                int d = t >> 3, k = t & 7;
                int l = k >> 2, h = k & 3;
                const float* We = l ? p.We2 : p.We1;
                const float* ae = l ? p.ae2 : p.ae1;
                float s = 0.f;
                #pragma unroll
                for (int c = 0; c < 16; ++c) s += We[d * HC + h * 16 + c] * ae[h * 16 + c];
                sVe[d * 8 + k] = s;
            }
            const float4* gsrc = (const float4*)p.ea + (size_t)ebid * 1024;
            #pragma unroll
            for (int r = 0; r < 4; ++r) {
                int i4 = t + r * 256;
                float4 v = gsrc[i4];
                float* dp = sE + (i4 >> 3) * 33 + ((i4 & 7) << 2);
                dp[0] = v.x; dp[1] = v.y; dp[2] = v.z; dp[3] = v.w;
            }
            __syncthreads();
            int el = t & 127;
            int kb = (t >> 7) * 4;
            long long e = (long long)ebid * 128 + el;
            const float* row = sE + el * 33;
            float a0 = 0.f, a1 = 0.f, a2 = 0.f, a3 = 0.f;
            #pragma unroll
            for (int c = 0; c < ED_DIM; ++c) {
                float ev = row[c];
                a0 += ev * sVe[c * 8 + kb];
                a1 += ev * sVe[c * 8 + kb + 1];
                a2 += ev * sVe[c * 8 + kb + 2];
                a3 += ev * sVe[c * 8 + kb + 3];
            }
            p.ale8[e * 2 + (t >> 7)] = make_float4(a0, a1, a2, a3);
        }
        __syncthreads();   // protect smem reuse across vb iterations
    }
    grid.sync();

    // ---- Phase C: per-block exclusive scan of cnt ----
    {
        int* sd = (int*)smem;
        for (int vb = blockIdx.x; vb < NBLK1; vb += nb) {
            int idx = vb * 256 + t;
            int v = (idx < N_NODES) ? p.cnt[idx] : 0;
            sd[t] = v; __syncthreads();
            for (int off = 1; off < 256; off <<= 1) {
                int add = (t >= off) ? sd[t - off] : 0;
                __syncthreads();
                sd[t] += add;
                __syncthreads();
            }
            if (idx < N_NODES) p.tmp_ex[idx] = sd[t] - v;
            if (t == 255) p.bsum[vb] = sd[t];
            __syncthreads();
        }
    }
    grid.sync();

    // ---- Phase D: row_start finalize + perm scatter ----
    {
        int* sd = (int*)smem;
        int* sboff = sd + 256;
        for (int vb = blockIdx.x; vb < NVB_D; vb += nb) {
            int v = (t < NBLK1) ? p.bsum[t] : 0;
            sd[t] = v; __syncthreads();
            for (int off = 1; off < 256; off <<= 1) {
                int add = (t >= off) ? sd[t - off] : 0;
                __syncthreads();
                sd[t] += add;
                __syncthreads();
            }
            sboff[t] = sd[t] - v;
            __syncthreads();
            if (vb < NBLK1) {
                int idx = vb * 256 + t;
                if (idx < N_NODES) p.row_start[idx] = p.tmp_ex[idx] + sboff[vb];
                if (idx == 0) p.row_start[N_NODES] = N_EDGES;
            } else {
                int e = (vb - NBLK1) * 256 + t;
                int d = p.dstI[e];
                int pos = p.tmp_ex[d] + sboff[d >> 8] + p.rank_e[e];
                p.perm_src[pos] = make_int2(e, p.srcI[e]);
            }
            __syncthreads();
        }
    }
    grid.sync();

    // ---- Phase E: agg layer 1 (+bias/ReLU/LN) fused with xw2 (R11-verified) ----
    {
        float* sW2 = smem;           // 16KB, staged ONCE per physical block
        float* sh  = smem + 4096;    // wave-private h rows
        for (int i = t; i < HC * HC; i += 256) sW2[i] = p.W2[i];
        __syncthreads();
        int wid = t >> 6, lane = t & 63, h = lane >> 4;
        for (int vb = blockIdx.x; vb < NVB_AGG; vb += nb) {
            int n = vb * 4 + wid;
            int e0 = p.row_start[n], e1 = p.row_start[n + 1];
            float adn = p.ald1[n * 4 + h];
            float acc0 = 0.f, l0 = 0.f, as0 = 0.f;
            float acc1 = 0.f, l1 = 0.f, as1 = 0.f;
            float acc2 = 0.f, l2 = 0.f, as2 = 0.f;
            float acc3 = 0.f, l3 = 0.f, as3 = 0.f;
            int e = e0;
            for (; e + 3 < e1; e += 4) {
                int2 pA = p.perm_src[e], pB = p.perm_src[e + 1];
                int2 pC = p.perm_src[e + 2], pD = p.perm_src[e + 3];
                float aeA = ((const float*)p.ale8)[(long long)pA.x * 8 + h];
                float aeB = ((const float*)p.ale8)[(long long)pB.x * 8 + h];
                float aeC = ((const float*)p.ale8)[(long long)pC.x * 8 + h];
                float aeD = ((const float*)p.ale8)[(long long)pD.x * 8 + h];
                float xA = p.xw1[pA.y * HC + lane];
                float xB = p.xw1[pB.y * HC + lane];
                float xC = p.xw1[pC.y * HC + lane];
                float xD = p.xw1[pD.y * HC + lane];
                float aA = p.als1[pA.y * 4 + h] + adn + aeA;
                float aB = p.als1[pB.y * 4 + h] + adn + aeB;
                float aC = p.als1[pC.y * 4 + h] + adn + aeC;
                float aD = p.als1[pD.y * 4 + h] + adn + aeD;
                aA = aA > 0.f ? aA : NEG_SLOPE * aA;
                aB = aB > 0.f ? aB : NEG_SLOPE * aB;
                aC = aC > 0.f ? aC : NEG_SLOPE * aC;
                aD = aD > 0.f ? aD : NEG_SLOPE * aD;
                float qA = __expf(aA), qB = __expf(aB), qC = __expf(aC), qD = __expf(aD);
                acc0 += qA * xA; l0 += qA; as0 += aeA;
                acc1 += qB * xB; l1 += qB; as1 += aeB;
                acc2 += qC * xC; l2 += qC; as2 += aeC;
                acc3 += qD * xD; l3 += qD; as3 += aeD;
            }
            for (; e < e1; ++e) {
                int2 pA = p.perm_src[e];
                float aeA = ((const float*)p.ale8)[(long long)pA.x * 8 + h];
                float xA = p.xw1[pA.y * HC + lane];
                float aA = p.als1[pA.y * 4 + h] + adn + aeA;
                aA = aA > 0.f ? aA : NEG_SLOPE * aA;
                float qA = __expf(aA);
                acc0 += qA * xA; l0 += qA; as0 += aeA;
            }
            int d = e1 - e0;
            float invd = 1.f / (float)(d > 0 ? d : 1);
            float aSelf = p.als1[n * 4 + h] + adn + (as0 + as1 + as2 + as3) * invd;
            aSelf = aSelf > 0.f ? aSelf : NEG_SLOPE * aSelf;
            float pS = __expf(aSelf);
            float acc = (acc0 + acc1) + (acc2 + acc3) + pS * p.xw1[n * HC + lane];
            float l = (l0 + l1) + (l2 + l3) + pS;
            float v = acc / (l + 1e-16f) + p.b1[lane];
            v = fmaxf(v, 0.f);
            {
                float s1 = v;
                #pragma unroll
                for (int mm = 1; mm < 64; mm <<= 1) s1 += __shfl_xor(s1, mm);
                float mean = s1 * (1.f / 64.f);
                float dd = v - mean;
                float s2 = dd * dd;
                #pragma unroll
                for (int mm = 1; mm < 64; mm <<= 1) s2 += __shfl_xor(s2, mm);
                float var = s2 * (1.f / 64.f);
                v = dd * rsqrtf(var + LN_EPS) * p.g1[lane] + p.be1[lane];
            }
            sh[wid * HC + lane] = v;   // wave-private: no barrier needed
            float a2 = 0.f;
            #pragma unroll 8
            for (int k = 0; k < HC; ++k) a2 += sh[wid * HC + k] * sW2[k * HC + lane];
            p.xw2[(long long)n * HC + lane] = a2;
            float vs = a2 * p.as2[lane], vd = a2 * p.ad2[lane];
            #pragma unroll
            for (int m = 1; m < 16; m <<= 1) { vs += __shfl_xor(vs, m); vd += __shfl_xor(vd, m); }
            if ((lane & 15) == 0) {
                p.als2[n * 4 + h] = vs; p.ald2[n * 4 + h] = vd;
            }
        }
    }
    grid.sync();

    // ---- Phase F: agg layer 2 (+bias/ReLU) -> h2 ----
    {
        int wid = t >> 6, lane = t & 63, h = lane >> 4;
        for (int vb = blockIdx.x; vb < NVB_AGG; vb += nb) {
            int n = vb * 4 + wid;
            int e0 = p.row_start[n], e1 = p.row_start[n + 1];
            float adn = p.ald2[n * 4 + h];
            float acc0 = 0.f, l0 = 0.f, as0 = 0.f;
            float acc1 = 0.f, l1 = 0.f, as1 = 0.f;
            float acc2 = 0.f, l2 = 0.f, as2 = 0.f;
            float acc3 = 0.f, l3 = 0.f, as3 = 0.f;
            int e = e0;
            for (; e + 3 < e1; e += 4) {
                int2 pA = p.perm_src[e], pB = p.perm_src[e + 1];
                int2 pC = p.perm_src[e + 2], pD = p.perm_src[e + 3];
                float aeA = ((const float*)p.ale8)[(long long)pA.x * 8 + 4 + h];
                float aeB = ((const float*)p.ale8)[(long long)pB.x * 8 + 4 + h];
                float aeC = ((const float*)p.ale8)[(long long)pC.x * 8 + 4 + h];
                float aeD = ((const float*)p.ale8)[(long long)pD.x * 8 + 4 + h];
                float xA = p.xw2[pA.y * HC + lane];
                float xB = p.xw2[pB.y * HC + lane];
                float xC = p.xw2[pC.y * HC + lane];
                float xD = p.xw2[pD.y * HC + lane];
                float aA = p.als2[pA.y * 4 + h] + adn + aeA;
                float aB = p.als2[pB.y * 4 + h] + adn + aeB;
                float aC = p.als2[pC.y * 4 + h] + adn + aeC;
                float aD = p.als2[pD.y * 4 + h] + adn + aeD;
                aA = aA > 0.f ? aA : NEG_SLOPE * aA;
                aB = aB > 0.f ? aB : NEG_SLOPE * aB;
                aC = aC > 0.f ? aC : NEG_SLOPE * aC;
                aD = aD > 0.f ? aD : NEG_SLOPE * aD;
                float qA = __expf(aA), qB = __expf(aB), qC = __expf(aC), qD = __expf(aD);
                acc0 += qA * xA; l0 += qA; as0 += aeA;
                acc1 += qB * xB; l1 += qB; as1 += aeB;
                acc2 += qC * xC; l2 += qC; as2 += aeC;
                acc3 += qD * xD; l3 += qD; as3 += aeD;
            }
            for (; e < e1; ++e) {
                int2 pA = p.perm_src[e];
                float aeA = ((const float*)p.ale8)[(long long)pA.x * 8 + 4 + h];
                float xA = p.xw2[pA.y * HC + lane];
                float aA = p.als2[pA.y * 4 + h] + adn + aeA;
                aA = aA > 0.f ? aA : NEG_SLOPE * aA;
                float qA = __expf(aA);
                acc0 += qA * xA; l0 += qA; as0 += aeA;
            }
            int d = e1 - e0;
            float invd = 1.f / (float)(d > 0 ? d : 1);
            float aSelf = p.als2[n * 4 + h] + adn + (as0 + as1 + as2 + as3) * invd;
            aSelf = aSelf > 0.f ? aSelf : NEG_SLOPE * aSelf;
            float pS = __expf(aSelf);
            float acc = (acc0 + acc1) + (acc2 + acc3) + pS * p.xw2[n * HC + lane];
            float l = (l0 + l1) + (l2 + l3) + pS;
            float v = acc / (l + 1e-16f) + p.b2[lane];
            v = fmaxf(v, 0.f);
            p.h2[(long long)n * HC + lane] = v;
        }
    }
    grid.sync();

    // ---- Phase G: global max pool ----
    for (int vb = blockIdx.x; vb < NVB_POOL; vb += nb) {
        int j = t & 63;
        int r = t >> 6;
        int base = vb * 128;
        int gcur = -1; float rm = 0.f;
        for (int n = base + r; n < base + 128 && n < N_NODES; n += 4) {
            int g = p.batch[n];
            if (g != gcur) {
                if (gcur >= 0) atomicMax((unsigned int*)&p.pooled[gcur * HC + j], __float_as_uint(rm));
                gcur = g; rm = 0.f;
            }
            rm = fmaxf(rm, p.h2[(long long)n * HC + j]);
        }
        if (gcur >= 0) atomicMax((unsigned int*)&p.pooled[gcur * HC + j], __float_as_uint(rm));
    }
    grid.sync();

    // ---- Phase H: head (4 groups per vblock, one per wave) ----
    for (int vb = blockIdx.x; vb < NVB_HEAD; vb += nb) {
        int g = vb * 4 + (t >> 6);
        int j = t & 63;
        float z = 0.f;
        if (j < 32) {
            for (int k = 0; k < HC; ++k) z += p.pooled[g * HC + k] * p.fw1[k * 32 + j];
            z += p.fb1[j];
        }
        float s1 = (j < 32) ? z : 0.f;
        for (int m = 1; m < 32; m <<= 1) s1 += __shfl_xor(s1, m, 32);
        float mean = s1 * (1.f / 32.f);
        float d = z - mean;
        float s2 = (j < 32) ? d * d : 0.f;
        for (int m = 1; m < 32; m <<= 1) s2 += __shfl_xor(s2, m, 32);
        float var = s2 * (1.f / 32.f);
        float zz = 0.f;
        if (j < 32) {
            zz = d * rsqrtf(var + LN_EPS) * p.g2[j] + p.be2[j];
            zz = fmaxf(zz, 0.f);
        }
        float p0 = (j < 32) ? zz * p.fw2[j * NCL + 0] : 0.f;
        float p1 = (j < 32) ? zz * p.fw2[j * NCL + 1] : 0.f;
        for (int m = 1; m < 32; m <<= 1) { p0 += __shfl_xor(p0, m, 32); p1 += __shfl_xor(p1, m, 32); }
        if (j == 0) {
            float l0 = p0 + p.fb2[0], l1 = p1 + p.fb2[1];
            float mx = fmaxf(l0, l1);
            float ls = mx + logf(__expf(l0 - mx) + __expf(l1 - mx));
            p.out[g * NCL + 0] = l0 - ls;
            p.out[g * NCL + 1] = l1 - ls;
        }
    }
}

// ================= Fallback path (R11 pipeline, used if cooperative unsupported) ======
__global__ __launch_bounds__(256) void k_phase1(
        const float* __restrict__ X, const float* __restrict__ W,
        const float* __restrict__ AS, const float* __restrict__ AD,
        float* __restrict__ XW, float* __restrict__ ALS, float* __restrict__ ALD,
        const float* __restrict__ ea,
        const float* __restrict__ We1, const float* __restrict__ ae1,
        const float* __restrict__ We2, const float* __restrict__ ae2,
        float4* __restrict__ ale8,
        const int* __restrict__ dst, int* __restrict__ cnt, int* __restrict__ rank_e) {
    __shared__ float smem[IN_DIM * HC + 16 * IN_DIM];
    int job = blockIdx.x % 3;
    int bid = blockIdx.x / 3;
    int t = threadIdx.x;
    if (job == 0) {
        const int K = IN_DIM;
        float* sW = smem;
        float* sX = smem + K * HC;
        for (int i = t; i < K * HC; i += 256) sW[i] = W[i];
        int nb = bid * 16;
        for (int i = t; i < 16 * K; i += 256) sX[i] = X[(long long)nb * K + i];
        __syncthreads();
        int sub = t >> 6, j = t & 63;
        float acc[4] = {0.f, 0.f, 0.f, 0.f};
        #pragma unroll 8
        for (int k = 0; k < K; ++k) {
            float wv = sW[k * HC + j];
            #pragma unroll
            for (int q = 0; q < 4; ++q) acc[q] += sX[(sub + 4 * q) * K + k] * wv;
        }
        float as_ = AS[j], ad_ = AD[j];
        #pragma unroll
        for (int q = 0; q < 4; ++q) {
            int n = nb + sub + 4 * q;
            XW[(long long)n * HC + j] = acc[q];
            float vs = acc[q] * as_, vd = acc[q] * ad_;
            #pragma unroll
            for (int m = 1; m < 16; m <<= 1) { vs += __shfl_xor(vs, m); vd += __shfl_xor(vd, m); }
            if ((j & 15) == 0) { int h = j >> 4; ALS[n * 4 + h] = vs; ALD[n * 4 + h] = vd; }
        }
    } else if (job == 1) {
        float* sVe = smem;
        float* sE  = smem + 256;
        {
            int d = t >> 3, k = t & 7;
            int l = k >> 2, h = k & 3;
            const float* We = l ? We2 : We1;
            const float* ae = l ? ae2 : ae1;
            float s = 0.f;
            #pragma unroll
            for (int c = 0; c < 16; ++c) s += We[d * HC + h * 16 + c] * ae[h * 16 + c];
            sVe[d * 8 + k] = s;
        }
        {
            const float4* gsrc = (const float4*)ea + (size_t)bid * 2048;
            #pragma unroll
            for (int r = 0; r < 8; ++r) {
                int i4 = t + r * 256;
                float4 v = gsrc[i4];
                float* dp = sE + (i4 >> 3) * 33 + ((i4 & 7) << 2);
                dp[0] = v.x; dp[1] = v.y; dp[2] = v.z; dp[3] = v.w;
            }
        }
        __syncthreads();
        int e = bid * 256 + t;
        float a[8];
        #pragma unroll
        for (int k = 0; k < 8; ++k) a[k] = 0.f;
        const float* row = sE + t * 33;
        #pragma unroll
        for (int c = 0; c < ED_DIM; ++c) {
            float ev = row[c];
            #pragma unroll
            for (int k = 0; k < 8; ++k) a[k] += ev * sVe[c * 8 + k];
        }
        float4* outp = ale8 + (long long)e * 2;
        outp[0] = make_float4(a[0], a[1], a[2], a[3]);
        outp[1] = make_float4(a[4], a[5], a[6], a[7]);
    } else {
        int e = bid * 256 + t;
        if (e < N_EDGES) rank_e[e] = atomicAdd(&cnt[dst[e]], 1);
    }
}

__global__ void k_scan_local(const int* __restrict__ cnt, int* __restrict__ tmp_ex,
                             int* __restrict__ bsum) {
    __shared__ int sd[256];
    int t = threadIdx.x, idx = blockIdx.x * 256 + t;
    int v = (idx < N_NODES) ? cnt[idx] : 0;
    sd[t] = v; __syncthreads();
    for (int off = 1; off < 256; off <<= 1) {
        int add = (t >= off) ? sd[t - off] : 0;
        __syncthreads();
        sd[t] += add;
        __syncthreads();
    }
    if (idx < N_NODES) tmp_ex[idx] = sd[t] - v;
    if (t == 255) bsum[blockIdx.x] = sd[t];
}

__global__ void k_scan_perm(const int* __restrict__ tmp_ex, const int* __restrict__ bsum,
                            int* __restrict__ row_start,
                            const int* __restrict__ dst, const int* __restrict__ srcI,
                            const int* __restrict__ rank_e, int2* __restrict__ perm_src) {
    __shared__ int sd[256];
    __shared__ int sboff[256];
    int t = threadIdx.x;
    int v = (t < NBLK1) ? bsum[t] : 0;
    sd[t] = v; __syncthreads();
    for (int off = 1; off < 256; off <<= 1) {
        int add = (t >= off) ? sd[t - off] : 0;
        __syncthreads();
        sd[t] += add;
        __syncthreads();
    }
    sboff[t] = sd[t] - v;
    __syncthreads();
    if (blockIdx.x < NBLK1) {
        int idx = blockIdx.x * 256 + t;
        if (idx < N_NODES) row_start[idx] = tmp_ex[idx] + sboff[blockIdx.x];
        if (idx == 0) row_start[N_NODES] = N_EDGES;
    } else {
        int e = (blockIdx.x - NBLK1) * 256 + t;
        if (e < N_EDGES) {
            int d = dst[e];
            int pos = tmp_ex[d] + sboff[d >> 8] + rank_e[e];
            perm_src[pos] = make_int2(e, srcI[e]);
        }
    }
}

__global__ __launch_bounds__(256) void k_agg1x(
        const int* __restrict__ rs, const int2* __restrict__ ps,
        const float* __restrict__ ale8,
        const float* __restrict__ ALS, const float* __restrict__ ALD,
        const float* __restrict__ XW, const float* __restrict__ bias,
        const float* __restrict__ gam, const float* __restrict__ bet,
        const float* __restrict__ W2,
        const float* __restrict__ AS2, const float* __restrict__ AD2,
        float* __restrict__ XW2, float* __restrict__ ALS2, float* __restrict__ ALD2) {
    __shared__ float sW2[HC * HC];
    __shared__ float sh[4][HC];
    int t = threadIdx.x;
    for (int i = t; i < HC * HC; i += 256) sW2[i] = W2[i];
    __syncthreads();
    int wid = t >> 6;
    int n = blockIdx.x * 4 + wid;
    int lane = t & 63;
    int h = lane >> 4;
    int e0 = rs[n], e1 = rs[n + 1];
    float adn = ALD[n * 4 + h];
    float acc0 = 0.f, l0 = 0.f, as0 = 0.f;
    float acc1 = 0.f, l1 = 0.f, as1 = 0.f;
    float acc2 = 0.f, l2 = 0.f, as2 = 0.f;
    float acc3 = 0.f, l3 = 0.f, as3 = 0.f;
    int e = e0;
    for (; e + 3 < e1; e += 4) {
        int2 pA = ps[e], pB = ps[e + 1], pC = ps[e + 2], pD = ps[e + 3];
        float aeA = ale8[(long long)pA.x * 8 + h];
        float aeB = ale8[(long long)pB.x * 8 + h];
        float aeC = ale8[(long long)pC.x * 8 + h];
        float aeD = ale8[(long long)pD.x * 8 + h];
        float xA = XW[pA.y * HC + lane];
        float xB = XW[pB.y * HC + lane];
        float xC = XW[pC.y * HC + lane];
        float xD = XW[pD.y * HC + lane];
        float aA = ALS[pA.y * 4 + h] + adn + aeA;
        float aB = ALS[pB.y * 4 + h] + adn + aeB;
        float aC = ALS[pC.y * 4 + h] + adn + aeC;
        float aD = ALS[pD.y * 4 + h] + adn + aeD;
        aA = aA > 0.f ? aA : NEG_SLOPE * aA;
        aB = aB > 0.f ? aB : NEG_SLOPE * aB;
        aC = aC > 0.f ? aC : NEG_SLOPE * aC;
        aD = aD > 0.f ? aD : NEG_SLOPE * aD;
        float qA = __expf(aA), qB = __expf(aB), qC = __expf(aC), qD = __expf(aD);
        acc0 += qA * xA; l0 += qA; as0 += aeA;
        acc1 += qB * xB; l1 += qB; as1 += aeB;
        acc2 += qC * xC; l2 += qC; as2 += aeC;
        acc3 += qD * xD; l3 += qD; as3 += aeD;
    }
    for (; e < e1; ++e) {
        int2 pA = ps[e];
        float aeA = ale8[(long long)pA.x * 8 + h];
        float xA = XW[pA.y * HC + lane];
        float aA = ALS[pA.y * 4 + h] + adn + aeA;
        aA = aA > 0.f ? aA : NEG_SLOPE * aA;
        float qA = __expf(aA);
        acc0 += qA * xA; l0 += qA; as0 += aeA;
    }
    int d = e1 - e0;
    float invd = 1.f / (float)(d > 0 ? d : 1);
    float aSelf = ALS[n * 4 + h] + adn + (as0 + as1 + as2 + as3) * invd;
    aSelf = aSelf > 0.f ? aSelf : NEG_SLOPE * aSelf;
    float pS = __expf(aSelf);
    float acc = (acc0 + acc1) + (acc2 + acc3) + pS * XW[n * HC + lane];
    float l = (l0 + l1) + (l2 + l3) + pS;
    float v = acc / (l + 1e-16f) + bias[lane];
    v = fmaxf(v, 0.f);
    {
        float s1 = v;
        #pragma unroll
        for (int mm = 1; mm < 64; mm <<= 1) s1 += __shfl_xor(s1, mm);
        float mean = s1 * (1.f / 64.f);
        float dd = v - mean;
        float s2 = dd * dd;
        #pragma unroll
        for (int mm = 1; mm < 64; mm <<= 1) s2 += __shfl_xor(s2, mm);
        float var = s2 * (1.f / 64.f);
        v = dd * rsqrtf(var + LN_EPS) * gam[lane] + bet[lane];
    }
    sh[wid][lane] = v;
    float a2 = 0.f;
    #pragma unroll 8
    for (int k = 0; k < HC; ++k) a2 += sh[wid][k] * sW2[k * HC + lane];
    XW2[(long long)n * HC + lane] = a2;
    float vs = a2 * AS2[lane], vd = a2 * AD2[lane];
    #pragma unroll
    for (int m = 1; m < 16; m <<= 1) { vs += __shfl_xor(vs, m); vd += __shfl_xor(vd, m); }
    if ((lane & 15) == 0) { ALS2[n * 4 + h] = vs; ALD2[n * 4 + h] = vd; }
}

__global__ void k_agg2(const int* __restrict__ rs, const int2* __restrict__ ps,
                       const float* __restrict__ ale8,
                       const float* __restrict__ ALS, const float* __restrict__ ALD,
                       const float* __restrict__ XW, const float* __restrict__ bias,
                       float* __restrict__ OUT) {
    int n = (blockIdx.x * blockDim.x + threadIdx.x) >> 6;
    if (n >= N_NODES) return;
    int lane = threadIdx.x & 63;
    int h = lane >> 4;
    int e0 = rs[n], e1 = rs[n + 1];
    float adn = ALD[n * 4 + h];
    float acc0 = 0.f, l0 = 0.f, as0 = 0.f;
    float acc1 = 0.f, l1 = 0.f, as1 = 0.f;
    float acc2 = 0.f, l2 = 0.f, as2 = 0.f;
    float acc3 = 0.f, l3 = 0.f, as3 = 0.f;
    int e = e0;
    for (; e + 3 < e1; e += 4) {
        int2 pA = ps[e], pB = ps[e + 1], pC = ps[e + 2], pD = ps[e + 3];
        float aeA = ale8[(long long)pA.x * 8 + 4 + h];
        float aeB = ale8[(long long)pB.x * 8 + 4 + h];
        float aeC = ale8[(long long)pC.x * 8 + 4 + h];
        float aeD = ale8[(long long)pD.x * 8 + 4 + h];
        float xA = XW[pA.y * HC + lane];
        float xB = XW[pB.y * HC + lane];
        float xC = XW[pC.y * HC + lane];
        float xD = XW[pD.y * HC + lane];
        float aA = ALS[pA.y * 4 + h] + adn + aeA;
        float aB = ALS[pB.y * 4 + h] + adn + aeB;
        float aC = ALS[pC.y * 4 + h] + adn + aeC;
        float aD = ALS[pD.y * 4 + h] + adn + aeD;
        aA = aA > 0.f ? aA : NEG_SLOPE * aA;
        aB = aB > 0.f ? aB : NEG_SLOPE * aB;
        aC = aC > 0.f ? aC : NEG_SLOPE * aC;
        aD = aD > 0.f ? aD : NEG_SLOPE * aD;
        float qA = __expf(aA), qB = __expf(aB), qC = __expf(aC), qD = __expf(aD);
        acc0 += qA * xA; l0 += qA; as0 += aeA;
        acc1 += qB * xB; l1 += qB; as1 += aeB;
        acc2 += qC * xC; l2 += qC; as2 += aeC;
        acc3 += qD * xD; l3 += qD; as3 += aeD;
    }
    for (; e < e1; ++e) {
        int2 pA = ps[e];
        float aeA = ale8[(long long)pA.x * 8 + 4 + h];
        float xA = XW[pA.y * HC + lane];
        float aA = ALS[pA.y * 4 + h] + adn + aeA;
        aA = aA > 0.f ? aA : NEG_SLOPE * aA;
        float qA = __expf(aA);
        acc0 += qA * xA; l0 += qA; as0 += aeA;
    }
    int d = e1 - e0;
    float invd = 1.f / (float)(d > 0 ? d : 1);
    float aSelf = ALS[n * 4 + h] + adn + (as0 + as1 + as2 + as3) * invd;
    aSelf = aSelf > 0.f ? aSelf : NEG_SLOPE * aSelf;
    float pS = __expf(aSelf);
    float acc = (acc0 + acc1) + (acc2 + acc3) + pS * XW[n * HC + lane];
    float l = (l0 + l1) + (l2 + l3) + pS;
    float v = acc / (l + 1e-16f) + bias[lane];
    v = fmaxf(v, 0.f);
    OUT[(long long)n * HC + lane] = v;
}

__global__ void k_pool(const float* __restrict__ H2, const int* __restrict__ batch,
                       float* __restrict__ pooled) {
    int j = threadIdx.x & 63;
    int r = threadIdx.x >> 6;
    int base = blockIdx.x * 128;
    int gcur = -1; float rm = 0.f;
    for (int n = base + r; n < base + 128 && n < N_NODES; n += 4) {
        int g = batch[n];
        if (g != gcur) {
            if (gcur >= 0) atomicMax((unsigned int*)&pooled[gcur * HC + j], __float_as_uint(rm));
            gcur = g; rm = 0.f;
        }
        rm = fmaxf(rm, H2[(long long)n * HC + j]);
    }
    if (gcur >= 0) atomicMax((unsigned int*)&pooled[gcur * HC + j], __float_as_uint(rm));
}

__global__ void k_head(const float* __restrict__ pooled,
                       const float* __restrict__ fw1, const float* __restrict__ fb1,
                       const float* __restrict__ g2, const float* __restrict__ be2,
                       const float* __restrict__ fw2, const float* __restrict__ fb2,
                       float* __restrict__ out) {
    int g = blockIdx.x;
    int j = threadIdx.x;
    float z = 0.f;
    if (j < 32) {
        for (int k = 0; k < HC; ++k) z += pooled[g * HC + k] * fw1[k * 32 + j];
        z += fb1[j];
    }
    float s1 = (j < 32) ? z : 0.f;
    for (int m = 1; m < 32; m <<= 1) s1 += __shfl_xor(s1, m, 32);
    float mean = s1 * (1.f / 32.f);
    float d = z - mean;
    float s2 = (j < 32) ? d * d : 0.f;
    for (int m = 1; m < 32; m <<= 1) s2 += __shfl_xor(s2, m, 32);
    float var = s2 * (1.f / 32.f);
    float zz = 0.f;
    if (j < 32) {
        zz = d * rsqrtf(var + LN_EPS) * g2[j] + be2[j];
        zz = fmaxf(zz, 0.f);
    }
    float p0 = (j < 32) ? zz * fw2[j * NCL + 0] : 0.f;
    float p1 = (j < 32) ? zz * fw2[j * NCL + 1] : 0.f;
    for (int m = 1; m < 32; m <<= 1) { p0 += __shfl_xor(p0, m, 32); p1 += __shfl_xor(p1, m, 32); }
    if (j == 0) {
        float l0 = p0 + fb2[0], l1 = p1 + fb2[1];
        float mx = fmaxf(l0, l1);
        float ls = mx + logf(__expf(l0 - mx) + __expf(l1 - mx));
        out[g * NCL + 0] = l0 - ls;
        out[g * NCL + 1] = l1 - ls;
    }
}

extern "C" void kernel_launch(void* const* d_in, const int* in_sizes, int n_in,
                              void* d_out, int out_size, void* d_ws, size_t ws_size,
                              hipStream_t stream) {
    const float* x   = (const float*)d_in[0];
    const float* ea  = (const float*)d_in[1];
    const float* W1  = (const float*)d_in[2];
    const float* as1 = (const float*)d_in[3];
    const float* ad1 = (const float*)d_in[4];
    const float* We1 = (const float*)d_in[5];
    const float* ae1 = (const float*)d_in[6];
    const float* b1  = (const float*)d_in[7];
    const float* W2  = (const float*)d_in[8];
    const float* as2 = (const float*)d_in[9];
    const float* ad2 = (const float*)d_in[10];
    const float* We2 = (const float*)d_in[11];
    const float* ae2 = (const float*)d_in[12];
    const float* b2  = (const float*)d_in[13];
    const float* g1  = (const float*)d_in[14];
    const float* be1 = (const float*)d_in[15];
    const float* fw1 = (const float*)d_in[16];
    const float* fb1 = (const float*)d_in[17];
    const float* g2  = (const float*)d_in[18];
    const float* be2 = (const float*)d_in[19];
    const float* fw2 = (const float*)d_in[20];
    const float* fb2 = (const float*)d_in[21];
    const int* eidx  = (const int*)d_in[22];
    const int* batch = (const int*)d_in[23];
    const int* srcI = eidx;
    const int* dstI = eidx + N_EDGES;

    char* w = (char*)d_ws;
    auto alloc = [&](size_t bytes) { char* p = w; w += (bytes + 255) & ~(size_t)255; return p; };
    int*   cnt       = (int*)  alloc((size_t)N_NODES * 4);
    int*   row_start = (int*)  alloc((size_t)(N_NODES + 1) * 4);
    int*   rank_e    = (int*)  alloc((size_t)N_EDGES * 4);
    int*   tmp_ex    = (int*)  alloc((size_t)N_NODES * 4);
    int*   bsum      = (int*)  alloc(256 * 4);
    int2*  perm_src  = (int2*) alloc((size_t)N_EDGES * 8);
    float4* ale8     = (float4*)alloc((size_t)N_EDGES * 32);
    float* xw1       = (float*)alloc((size_t)N_NODES * HC * 4);
    float* als1      = (float*)alloc((size_t)N_NODES * 4 * 4);
    float* ald1      = (float*)alloc((size_t)N_NODES * 4 * 4);
    float* xw2       = (float*)alloc((size_t)N_NODES * HC * 4);
    float* als2      = (float*)alloc((size_t)N_NODES * 4 * 4);
    float* ald2      = (float*)alloc((size_t)N_NODES * 4 * 4);
    float* h2        = (float*)alloc((size_t)N_NODES * HC * 4);
    float* pooled    = (float*)alloc((size_t)NG * HC * 4);

    // one-time capability + grid sizing (static: runs once, capture-safe queries only)
    static int coopBlocks = -1;
    if (coopBlocks < 0) {
        int dev = 0; hipGetDevice(&dev);
        hipDeviceProp_t prop;
        int nCU = 256, coop = 0;
        if (hipGetDeviceProperties(&prop, dev) == hipSuccess) {
            nCU = prop.multiProcessorCount;
            coop = prop.cooperativeLaunch;
        }
        int perCU = 0;
        if (coop &&
            hipOccupancyMaxActiveBlocksPerMultiprocessor(&perCU, mega, 256, 0) == hipSuccess &&
            perCU > 0) {
            coopBlocks = perCU * nCU;
        } else {
            coopBlocks = 0;   // fallback path
        }
    }

    if (coopBlocks > 0) {
        MParams P;
        P.x = x; P.ea = ea; P.W1 = W1; P.as1 = as1; P.ad1 = ad1;
        P.We1 = We1; P.ae1 = ae1; P.b1 = b1;
        P.W2 = W2; P.as2 = as2; P.ad2 = ad2; P.We2 = We2; P.ae2 = ae2; P.b2 = b2;
        P.g1 = g1; P.be1 = be1; P.fw1 = fw1; P.fb1 = fb1;
        P.g2 = g2; P.be2 = be2; P.fw2 = fw2; P.fb2 = fb2;
        P.srcI = srcI; P.dstI = dstI; P.batch = batch;
        P.cnt = cnt; P.row_start = row_start; P.rank_e = rank_e;
        P.tmp_ex = tmp_ex; P.bsum = bsum; P.perm_src = perm_src; P.ale8 = ale8;
        P.xw1 = xw1; P.als1 = als1; P.ald1 = ald1;
        P.xw2 = xw2; P.als2 = als2; P.ald2 = ald2;
        P.h2 = h2; P.pooled = pooled; P.out = (float*)d_out;
        void* kargs[] = { (void*)&P };
        hipError_t err = hipLaunchCooperativeKernel((void*)mega, dim3(coopBlocks),
                                                    dim3(256), kargs, 0, stream);
        if (err == hipSuccess) return;
        coopBlocks = 0;   // launch rejected -> use fallback from now on
    }

    // -------- fallback: R11 pipeline --------
    hipMemsetAsync(cnt, 0, (size_t)N_NODES * 4, stream);
    hipMemsetAsync(pooled, 0, (size_t)NG * HC * 4, stream);
    k_phase1<<<3 * NB_TILE, 256, 0, stream>>>(x, W1, as1, ad1, xw1, als1, ald1,
                                              ea, We1, ae1, We2, ae2, ale8,
                                              dstI, cnt, rank_e);
    k_scan_local<<<NBLK1, 256, 0, stream>>>(cnt, tmp_ex, bsum);
    k_scan_perm<<<NBLK1 + NB_TILE, 256, 0, stream>>>(tmp_ex, bsum, row_start,
                                                     dstI, srcI, rank_e, perm_src);
    k_agg1x<<<N_NODES / 4, 256, 0, stream>>>(row_start, perm_src, (const float*)ale8,
                                             als1, ald1, xw1, b1, g1, be1,
                                             W2, as2, ad2, xw2, als2, ald2);
    k_agg2<<<N_NODES / 4, 256, 0, stream>>>(row_start, perm_src, (const float*)ale8,
                                            als2, ald2, xw2, b2, h2);
    k_pool<<<(N_NODES + 127) / 128, 256, 0, stream>>>(h2, batch, pooled);
    k_head<<<NG, 64, 0, stream>>>(pooled, fw1, fb1, g2, be2, fw2, fb2, (float*)d_out);
}

// Round 14
// 424.071 us; speedup vs baseline: 3.6298x; 3.6298x over previous
//
#include <hip/hip_runtime.h>
#include <math.h>

#define N_NODES 50000
#define N_EDGES 800000
#define IN_DIM 128
#define ED_DIM 32
#define HC 64
#define NG 64
#define NCL 2
#define NEG_SLOPE 0.2f
#define LN_EPS 1e-5f
#define NBLK1 196   // ceil(50000/256)
#define NB_TILE 3125  // 50000/16 xw tiles == 800000/256 edge chunks

// ---------- scan phase 1: per-block exclusive scan of cnt ----------
__global__ void k_scan_local(const int* __restrict__ cnt, int* __restrict__ tmp_ex,
                             int* __restrict__ bsum) {
    __shared__ int sd[256];
    int t = threadIdx.x, idx = blockIdx.x * 256 + t;
    int v = (idx < N_NODES) ? cnt[idx] : 0;
    sd[t] = v; __syncthreads();
    for (int off = 1; off < 256; off <<= 1) {
        int add = (t >= off) ? sd[t - off] : 0;
        __syncthreads();
        sd[t] += add;
        __syncthreads();
    }
    if (idx < N_NODES) tmp_ex[idx] = sd[t] - v;
    if (t == 255) bsum[blockIdx.x] = sd[t];
}

// ---------- fused phase 1: {xw1 | edge projection | degree hist} by blockIdx%3 ----------
// R10-proven (73.5us): job1 stages its 256 edge rows via coalesced float4 loads
// into padded LDS (stride 33, bank-conflict-free), cutting ea vmem transactions 4x.
__global__ __launch_bounds__(256) void k_phase1(
        const float* __restrict__ X, const float* __restrict__ W,
        const float* __restrict__ AS, const float* __restrict__ AD,
        float* __restrict__ XW, float* __restrict__ ALS, float* __restrict__ ALD,
        const float* __restrict__ ea,
        const float* __restrict__ We1, const float* __restrict__ ae1,
        const float* __restrict__ We2, const float* __restrict__ ae2,
        float4* __restrict__ ale8,
        const int* __restrict__ dst, int* __restrict__ cnt, int* __restrict__ rank_e) {
    __shared__ float smem[IN_DIM * HC + 16 * IN_DIM];   // 40 KB, reused by all jobs
    int job = blockIdx.x % 3;
    int bid = blockIdx.x / 3;
    int t = threadIdx.x;
    if (job == 0) {
        const int K = IN_DIM;
        float* sW = smem;
        float* sX = smem + K * HC;
        for (int i = t; i < K * HC; i += 256) sW[i] = W[i];
        int nb = bid * 16;
        for (int i = t; i < 16 * K; i += 256) sX[i] = X[(long long)nb * K + i];
        __syncthreads();
        int sub = t >> 6, j = t & 63;
        float acc[4] = {0.f, 0.f, 0.f, 0.f};
        #pragma unroll 8
        for (int k = 0; k < K; ++k) {
            float wv = sW[k * HC + j];
            #pragma unroll
            for (int q = 0; q < 4; ++q) acc[q] += sX[(sub + 4 * q) * K + k] * wv;
        }
        float as_ = AS[j], ad_ = AD[j];
        #pragma unroll
        for (int q = 0; q < 4; ++q) {
            int n = nb + sub + 4 * q;
            XW[(long long)n * HC + j] = acc[q];
            float vs = acc[q] * as_, vd = acc[q] * ad_;
            #pragma unroll
            for (int m = 1; m < 16; m <<= 1) { vs += __shfl_xor(vs, m); vd += __shfl_xor(vd, m); }
            if ((j & 15) == 0) {
                int h = j >> 4;
                ALS[n * 4 + h] = vs; ALD[n * 4 + h] = vd;
            }
        }
    } else if (job == 1) {
        float* sVe = smem;              // 256 floats
        float* sE  = smem + 256;        // 256 edges x 33 words (padded) = 33.8 KB
        {
            int d = t >> 3, k = t & 7;
            int l = k >> 2, h = k & 3;
            const float* We = l ? We2 : We1;
            const float* ae = l ? ae2 : ae1;
            float s = 0.f;
            #pragma unroll
            for (int c = 0; c < 16; ++c) s += We[d * HC + h * 16 + c] * ae[h * 16 + c];
            sVe[d * 8 + k] = s;
        }
        // coalesced staging of this block's 256 edge rows (2048 float4s)
        {
            const float4* gsrc = (const float4*)ea + (size_t)bid * 2048;
            #pragma unroll
            for (int r = 0; r < 8; ++r) {
                int i4 = t + r * 256;
                float4 v = gsrc[i4];
                float* dp = sE + (i4 >> 3) * 33 + ((i4 & 7) << 2);
                dp[0] = v.x; dp[1] = v.y; dp[2] = v.z; dp[3] = v.w;
            }
        }
        __syncthreads();
        int e = bid * 256 + t;
        float a[8];
        #pragma unroll
        for (int k = 0; k < 8; ++k) a[k] = 0.f;
        const float* row = sE + t * 33;   // bank = (t+i)%32 -> 2 lanes/bank, free
        #pragma unroll
        for (int c = 0; c < ED_DIM; ++c) {
            float ev = row[c];
            #pragma unroll
            for (int k = 0; k < 8; ++k) a[k] += ev * sVe[c * 8 + k];
        }
        float4* outp = ale8 + (long long)e * 2;
        outp[0] = make_float4(a[0], a[1], a[2], a[3]);
        outp[1] = make_float4(a[4], a[5], a[6], a[7]);
    } else {
        int e = bid * 256 + t;
        if (e < N_EDGES) rank_e[e] = atomicAdd(&cnt[dst[e]], 1);
    }
}

// ---------- fused: row_start finalize + perm scatter ----------
__global__ void k_scan_perm(const int* __restrict__ tmp_ex, const int* __restrict__ bsum,
                            int* __restrict__ row_start,
                            const int* __restrict__ dst, const int* __restrict__ srcI,
                            const int* __restrict__ rank_e, int2* __restrict__ perm_src) {
    __shared__ int sd[256];
    __shared__ int sboff[256];
    int t = threadIdx.x;
    int v = (t < NBLK1) ? bsum[t] : 0;
    sd[t] = v; __syncthreads();
    for (int off = 1; off < 256; off <<= 1) {
        int add = (t >= off) ? sd[t - off] : 0;
        __syncthreads();
        sd[t] += add;
        __syncthreads();
    }
    sboff[t] = sd[t] - v;   // exclusive prefix of bsum
    __syncthreads();
    if (blockIdx.x < NBLK1) {
        int idx = blockIdx.x * 256 + t;
        if (idx < N_NODES) row_start[idx] = tmp_ex[idx] + sboff[blockIdx.x];
        if (idx == 0) row_start[N_NODES] = N_EDGES;
    } else {
        int e = (blockIdx.x - NBLK1) * 256 + t;
        if (e < N_EDGES) {
            int d = dst[e];
            int pos = tmp_ex[d] + sboff[d >> 8] + rank_e[e];
            perm_src[pos] = make_int2(e, srcI[e]);
        }
    }
}

// ---------- agg layer 1 (+bias/ReLU/LN) fused with xw2 = h1 @ W2 + layer-2 logits ----------
// R11-verified (82.4us, VALU 67.7%): W2 staged once per block in LDS; single
// fixed-cost barrier; h-row through wave-private LDS; k ascending = bit-exact.
__global__ __launch_bounds__(256) void k_agg1x(
        const int* __restrict__ rs, const int2* __restrict__ ps,
        const float* __restrict__ ale8,
        const float* __restrict__ ALS, const float* __restrict__ ALD,
        const float* __restrict__ XW, const float* __restrict__ bias,
        const float* __restrict__ gam, const float* __restrict__ bet,
        const float* __restrict__ W2,
        const float* __restrict__ AS2, const float* __restrict__ AD2,
        float* __restrict__ XW2, float* __restrict__ ALS2, float* __restrict__ ALD2) {
    __shared__ float sW2[HC * HC];   // 16 KB
    __shared__ float sh[4][HC];      // wave-private h rows
    int t = threadIdx.x;
    for (int i = t; i < HC * HC; i += 256) sW2[i] = W2[i];
    __syncthreads();                 // single fixed-cost barrier
    int wid = t >> 6;
    int n = blockIdx.x * 4 + wid;    // grid is exactly N_NODES/4
    int lane = t & 63;
    int h = lane >> 4;
    int e0 = rs[n], e1 = rs[n + 1];
    float adn = ALD[n * 4 + h];
    float acc0 = 0.f, l0 = 0.f, as0 = 0.f;
    float acc1 = 0.f, l1 = 0.f, as1 = 0.f;
    float acc2 = 0.f, l2 = 0.f, as2 = 0.f;
    float acc3 = 0.f, l3 = 0.f, as3 = 0.f;
    int e = e0;
    for (; e + 3 < e1; e += 4) {
        int2 pA = ps[e], pB = ps[e + 1], pC = ps[e + 2], pD = ps[e + 3];
        float aeA = ale8[(long long)pA.x * 8 + h];
        float aeB = ale8[(long long)pB.x * 8 + h];
        float aeC = ale8[(long long)pC.x * 8 + h];
        float aeD = ale8[(long long)pD.x * 8 + h];
        float xA = XW[pA.y * HC + lane];
        float xB = XW[pB.y * HC + lane];
        float xC = XW[pC.y * HC + lane];
        float xD = XW[pD.y * HC + lane];
        float aA = ALS[pA.y * 4 + h] + adn + aeA;
        float aB = ALS[pB.y * 4 + h] + adn + aeB;
        float aC = ALS[pC.y * 4 + h] + adn + aeC;
        float aD = ALS[pD.y * 4 + h] + adn + aeD;
        aA = aA > 0.f ? aA : NEG_SLOPE * aA;
        aB = aB > 0.f ? aB : NEG_SLOPE * aB;
        aC = aC > 0.f ? aC : NEG_SLOPE * aC;
        aD = aD > 0.f ? aD : NEG_SLOPE * aD;
        float qA = __expf(aA), qB = __expf(aB), qC = __expf(aC), qD = __expf(aD);
        acc0 += qA * xA; l0 += qA; as0 += aeA;
        acc1 += qB * xB; l1 += qB; as1 += aeB;
        acc2 += qC * xC; l2 += qC; as2 += aeC;
        acc3 += qD * xD; l3 += qD; as3 += aeD;
    }
    for (; e < e1; ++e) {
        int2 pA = ps[e];
        float aeA = ale8[(long long)pA.x * 8 + h];
        float xA = XW[pA.y * HC + lane];
        float aA = ALS[pA.y * 4 + h] + adn + aeA;
        aA = aA > 0.f ? aA : NEG_SLOPE * aA;
        float qA = __expf(aA);
        acc0 += qA * xA; l0 += qA; as0 += aeA;
    }
    int d = e1 - e0;
    float invd = 1.f / (float)(d > 0 ? d : 1);
    float aSelf = ALS[n * 4 + h] + adn + (as0 + as1 + as2 + as3) * invd;
    aSelf = aSelf > 0.f ? aSelf : NEG_SLOPE * aSelf;
    float pS = __expf(aSelf);
    float acc = (acc0 + acc1) + (acc2 + acc3) + pS * XW[n * HC + lane];
    float l = (l0 + l1) + (l2 + l3) + pS;
    float v = acc / (l + 1e-16f) + bias[lane];
    v = fmaxf(v, 0.f);
    {
        float s1 = v;
        #pragma unroll
        for (int mm = 1; mm < 64; mm <<= 1) s1 += __shfl_xor(s1, mm);
        float mean = s1 * (1.f / 64.f);
        float dd = v - mean;
        float s2 = dd * dd;
        #pragma unroll
        for (int mm = 1; mm < 64; mm <<= 1) s2 += __shfl_xor(s2, mm);
        float var = s2 * (1.f / 64.f);
        v = dd * rsqrtf(var + LN_EPS) * gam[lane] + bet[lane];
    }
    sh[wid][lane] = v;   // wave-private: no barrier needed
    float a2 = 0.f;
    #pragma unroll 8
    for (int k = 0; k < HC; ++k) a2 += sh[wid][k] * sW2[k * HC + lane];
    XW2[(long long)n * HC + lane] = a2;
    float vs = a2 * AS2[lane], vd = a2 * AD2[lane];
    #pragma unroll
    for (int m = 1; m < 16; m <<= 1) { vs += __shfl_xor(vs, m); vd += __shfl_xor(vd, m); }
    if ((lane & 15) == 0) { ALS2[n * 4 + h] = vs; ALD2[n * 4 + h] = vd; }
}

// ---------- layer-2 aggregation (+bias/ReLU) fused with per-lane max pool ----------
// R4-verified form (86.7us standalone, passed): h2 never materialized; each lane
// atomicMax's into pooled[batch[n]]. Max is order-independent and float-as-uint
// preserves order for values >= 0 -> bit-exact. No inter-wave coupling (R5's bug).
__global__ void k_agg2p(const int* __restrict__ rs, const int2* __restrict__ ps,
                        const float* __restrict__ ale8,
                        const float* __restrict__ ALS, const float* __restrict__ ALD,
                        const float* __restrict__ XW, const float* __restrict__ bias,
                        const int* __restrict__ batch, float* __restrict__ pooled) {
    int n = (blockIdx.x * blockDim.x + threadIdx.x) >> 6;
    if (n >= N_NODES) return;
    int lane = threadIdx.x & 63;
    int h = lane >> 4;
    int e0 = rs[n], e1 = rs[n + 1];
    float adn = ALD[n * 4 + h];
    float acc0 = 0.f, l0 = 0.f, as0 = 0.f;
    float acc1 = 0.f, l1 = 0.f, as1 = 0.f;
    float acc2 = 0.f, l2 = 0.f, as2 = 0.f;
    float acc3 = 0.f, l3 = 0.f, as3 = 0.f;
    int e = e0;
    for (; e + 3 < e1; e += 4) {
        int2 pA = ps[e], pB = ps[e + 1], pC = ps[e + 2], pD = ps[e + 3];
        float aeA = ale8[(long long)pA.x * 8 + 4 + h];
        float aeB = ale8[(long long)pB.x * 8 + 4 + h];
        float aeC = ale8[(long long)pC.x * 8 + 4 + h];
        float aeD = ale8[(long long)pD.x * 8 + 4 + h];
        float xA = XW[pA.y * HC + lane];
        float xB = XW[pB.y * HC + lane];
        float xC = XW[pC.y * HC + lane];
        float xD = XW[pD.y * HC + lane];
        float aA = ALS[pA.y * 4 + h] + adn + aeA;
        float aB = ALS[pB.y * 4 + h] + adn + aeB;
        float aC = ALS[pC.y * 4 + h] + adn + aeC;
        float aD = ALS[pD.y * 4 + h] + adn + aeD;
        aA = aA > 0.f ? aA : NEG_SLOPE * aA;
        aB = aB > 0.f ? aB : NEG_SLOPE * aB;
        aC = aC > 0.f ? aC : NEG_SLOPE * aC;
        aD = aD > 0.f ? aD : NEG_SLOPE * aD;
        float qA = __expf(aA), qB = __expf(aB), qC = __expf(aC), qD = __expf(aD);
        acc0 += qA * xA; l0 += qA; as0 += aeA;
        acc1 += qB * xB; l1 += qB; as1 += aeB;
        acc2 += qC * xC; l2 += qC; as2 += aeC;
        acc3 += qD * xD; l3 += qD; as3 += aeD;
    }
    for (; e < e1; ++e) {
        int2 pA = ps[e];
        float aeA = ale8[(long long)pA.x * 8 + 4 + h];
        float xA = XW[pA.y * HC + lane];
        float aA = ALS[pA.y * 4 + h] + adn + aeA;
        aA = aA > 0.f ? aA : NEG_SLOPE * aA;
        float qA = __expf(aA);
        acc0 += qA * xA; l0 += qA; as0 += aeA;
    }
    int d = e1 - e0;
    float invd = 1.f / (float)(d > 0 ? d : 1);
    float aSelf = ALS[n * 4 + h] + adn + (as0 + as1 + as2 + as3) * invd;
    aSelf = aSelf > 0.f ? aSelf : NEG_SLOPE * aSelf;
    float pS = __expf(aSelf);
    float acc = (acc0 + acc1) + (acc2 + acc3) + pS * XW[n * HC + lane];
    float l = (l0 + l1) + (l2 + l3) + pS;
    float v = acc / (l + 1e-16f) + bias[lane];
    v = fmaxf(v, 0.f);
    int g = batch[n];
    atomicMax((unsigned int*)&pooled[g * HC + lane], __float_as_uint(v));
}

// ---------- head: fc1 + LN + relu + fc2 + log_softmax ----------
__global__ void k_head(const float* __restrict__ pooled,
                       const float* __restrict__ fw1, const float* __restrict__ fb1,
                       const float* __restrict__ g2, const float* __restrict__ be2,
                       const float* __restrict__ fw2, const float* __restrict__ fb2,
                       float* __restrict__ out) {
    int g = blockIdx.x;
    int j = threadIdx.x;                // 64 threads, lanes 0..31 active for math
    float z = 0.f;
    if (j < 32) {
        for (int k = 0; k < HC; ++k) z += pooled[g * HC + k] * fw1[k * 32 + j];
        z += fb1[j];
    }
    float s1 = (j < 32) ? z : 0.f;
    for (int m = 1; m < 32; m <<= 1) s1 += __shfl_xor(s1, m, 32);
    float mean = s1 * (1.f / 32.f);
    float d = z - mean;
    float s2 = (j < 32) ? d * d : 0.f;
    for (int m = 1; m < 32; m <<= 1) s2 += __shfl_xor(s2, m, 32);
    float var = s2 * (1.f / 32.f);
    float zz = 0.f;
    if (j < 32) {
        zz = d * rsqrtf(var + LN_EPS) * g2[j] + be2[j];
        zz = fmaxf(zz, 0.f);
    }
    float p0 = (j < 32) ? zz * fw2[j * NCL + 0] : 0.f;
    float p1 = (j < 32) ? zz * fw2[j * NCL + 1] : 0.f;
    for (int m = 1; m < 32; m <<= 1) { p0 += __shfl_xor(p0, m, 32); p1 += __shfl_xor(p1, m, 32); }
    if (j == 0) {
        float l0 = p0 + fb2[0], l1 = p1 + fb2[1];
        float mx = fmaxf(l0, l1);
        float ls = mx + logf(__expf(l0 - mx) + __expf(l1 - mx));
        out[g * NCL + 0] = l0 - ls;
        out[g * NCL + 1] = l1 - ls;
    }
}

extern "C" void kernel_launch(void* const* d_in, const int* in_sizes, int n_in,
                              void* d_out, int out_size, void* d_ws, size_t ws_size,
                              hipStream_t stream) {
    const float* x   = (const float*)d_in[0];
    const float* ea  = (const float*)d_in[1];
    const float* W1  = (const float*)d_in[2];
    const float* as1 = (const float*)d_in[3];
    const float* ad1 = (const float*)d_in[4];
    const float* We1 = (const float*)d_in[5];
    const float* ae1 = (const float*)d_in[6];
    const float* b1  = (const float*)d_in[7];
    const float* W2  = (const float*)d_in[8];
    const float* as2 = (const float*)d_in[9];
    const float* ad2 = (const float*)d_in[10];
    const float* We2 = (const float*)d_in[11];
    const float* ae2 = (const float*)d_in[12];
    const float* b2  = (const float*)d_in[13];
    const float* g1  = (const float*)d_in[14];
    const float* be1 = (const float*)d_in[15];
    const float* fw1 = (const float*)d_in[16];
    const float* fb1 = (const float*)d_in[17];
    const float* g2  = (const float*)d_in[18];
    const float* be2 = (const float*)d_in[19];
    const float* fw2 = (const float*)d_in[20];
    const float* fb2 = (const float*)d_in[21];
    const int* eidx  = (const int*)d_in[22];
    const int* batch = (const int*)d_in[23];
    const int* srcI = eidx;
    const int* dstI = eidx + N_EDGES;

    char* w = (char*)d_ws;
    auto alloc = [&](size_t bytes) { char* p = w; w += (bytes + 255) & ~(size_t)255; return p; };
    int*   cnt       = (int*)  alloc((size_t)N_NODES * 4);
    int*   row_start = (int*)  alloc((size_t)(N_NODES + 1) * 4);
    int*   rank_e    = (int*)  alloc((size_t)N_EDGES * 4);
    int*   tmp_ex    = (int*)  alloc((size_t)N_NODES * 4);
    int*   bsum      = (int*)  alloc(256 * 4);
    int2*  perm_src  = (int2*) alloc((size_t)N_EDGES * 8);
    float4* ale8     = (float4*)alloc((size_t)N_EDGES * 32);
    float* xw1       = (float*)alloc((size_t)N_NODES * HC * 4);
    float* als1      = (float*)alloc((size_t)N_NODES * 4 * 4);
    float* ald1      = (float*)alloc((size_t)N_NODES * 4 * 4);
    float* xw2       = (float*)alloc((size_t)N_NODES * HC * 4);  // agg1x reads xw1 while writing xw2
    float* als2      = (float*)alloc((size_t)N_NODES * 4 * 4);
    float* ald2      = (float*)alloc((size_t)N_NODES * 4 * 4);
    float* pooled    = (float*)alloc((size_t)NG * HC * 4);

    hipMemsetAsync(cnt, 0, (size_t)N_NODES * 4, stream);
    hipMemsetAsync(pooled, 0, (size_t)NG * HC * 4, stream);

    // Phase 1: xw1 | edge projection | degree hist — independent, one dispatch
    k_phase1<<<3 * NB_TILE, 256, 0, stream>>>(x, W1, as1, ad1, xw1, als1, ald1,
                                              ea, We1, ae1, We2, ae2, ale8,
                                              dstI, cnt, rank_e);
    k_scan_local<<<NBLK1, 256, 0, stream>>>(cnt, tmp_ex, bsum);
    // row_start finalize + perm scatter in one dispatch
    k_scan_perm<<<NBLK1 + NB_TILE, 256, 0, stream>>>(tmp_ex, bsum, row_start,
                                                     dstI, srcI, rank_e, perm_src);

    // Layer 1 aggregate (+bias/ReLU/LN) fused with xw2 GEMM (block-shared LDS W2)
    k_agg1x<<<N_NODES / 4, 256, 0, stream>>>(row_start, perm_src, (const float*)ale8,
                                             als1, ald1, xw1, b1, g1, be1,
                                             W2, as2, ad2, xw2, als2, ald2);
    // Layer 2 aggregate (+bias/ReLU) fused with per-lane max pool (h2 eliminated)
    k_agg2p<<<N_NODES / 4, 256, 0, stream>>>(row_start, perm_src, (const float*)ale8,
                                             als2, ald2, xw2, b2, batch, pooled);

    k_head<<<NG, 64, 0, stream>>>(pooled, fw1, fb1, g2, be2, fw2, fb2, (float*)d_out);
}